// Round 1
// baseline (613.957 us; speedup 1.0000x reference)
//
#include <hip/hip_runtime.h>

// MPS chain evaluation, restructured:
//   out[b,o] = vleft[b,:] . Mlabel_b[:,:,o] . rvec[b,:]
// where vleft is the forward left-chain vector (sites 0..391) and rvec is the
// BACKWARD-propagated right-chain vector (sites 782..393 applied to the
// w_last boundary). This avoids carrying the [D,O] tensor through the right
// scan (704 FMA/site -> 136 FMA/site).
//
// Layout: block = 128 threads = 2 waves; wave 0 does left chains for 64
// batches (one per lane), wave 1 does right chains for the same 64 batches.
// grid = 256 blocks = B/64 -> one block per CU, 2 waves/CU.
// Precision: everything fp32 (threshold is ~2% of max |ref| over a 781-site
// chain; bf16/MFMA would accumulate ~5-10% relative error).

#define BATCH  16384
#define NSITES 784
#define DIM    8
#define ODIM   10
#define LABEL  392
#define L_LEFT 391   // sites 1..391
#define L_RIGHT 390  // sites 393..782

__global__ __launch_bounds__(128) void mps_chain_kernel(
    const float* __restrict__ x,      // [B, N]  (trailing dim 1 squeezed)
    const float* __restrict__ w0,     // [2, D]
    const float* __restrict__ Wl,     // [L_LEFT, D, 2, D]
    const float* __restrict__ wlab,   // [D, 2, D, O]
    const float* __restrict__ Wr,     // [L_RIGHT, D, 2, D]
    const float* __restrict__ wlast,  // [D, 2]
    float* __restrict__ out)          // [B, O]
{
    __shared__ float vl[64][DIM];   // left-chain result per batch lane
    __shared__ float rv[64][DIM];   // right-chain (backward) result per batch lane

    const int lane = threadIdx.x & 63;
    const int wave = threadIdx.x >> 6;
    const int base = blockIdx.x * 64;
    const int b    = base + lane;
    const float* xr = x + (size_t)b * NSITES;

    if (wave == 0) {
        // ---- forward left chain: v <- v^T * M_i, i = 1..391 ----
        float v[DIM];
        {
            float p = xr[0];
            float q = 1.0f - p;
            #pragma unroll
            for (int d = 0; d < DIM; ++d)
                v[d] = q * w0[d] + p * w0[DIM + d];   // phi0*w0[0,d] + phi1*w0[1,d]
        }
        for (int i = 1; i <= L_LEFT; ++i) {
            const float* w = Wl + (size_t)(i - 1) * (DIM * 2 * DIM); // [d][f][e]
            const float pi = xr[i];
            const float qi = 1.0f - pi;
            float a0[DIM], a1[DIM];
            #pragma unroll
            for (int e = 0; e < DIM; ++e) { a0[e] = 0.0f; a1[e] = 0.0f; }
            #pragma unroll
            for (int d = 0; d < DIM; ++d) {
                const float vd = v[d];
                #pragma unroll
                for (int e = 0; e < DIM; ++e) {
                    a0[e] = fmaf(vd, w[d * 16 + e],     a0[e]);   // f = 0
                    a1[e] = fmaf(vd, w[d * 16 + 8 + e], a1[e]);   // f = 1
                }
            }
            #pragma unroll
            for (int e = 0; e < DIM; ++e)
                v[e] = fmaf(qi, a0[e], pi * a1[e]);
        }
        #pragma unroll
        for (int d = 0; d < DIM; ++d) vl[lane][d] = v[d];
    } else {
        // ---- backward right chain: r <- M_i * r, i = 782 down to 393 ----
        float r[DIM];
        {
            float p = xr[NSITES - 1];
            float q = 1.0f - p;
            #pragma unroll
            for (int d = 0; d < DIM; ++d)
                r[d] = q * wlast[d * 2] + p * wlast[d * 2 + 1];
        }
        for (int i = NSITES - 2; i > LABEL; --i) {
            const float* w = Wr + (size_t)(i - (LABEL + 1)) * (DIM * 2 * DIM);
            const float pi = xr[i];
            const float qi = 1.0f - pi;
            float a0[DIM], a1[DIM];
            #pragma unroll
            for (int d = 0; d < DIM; ++d) { a0[d] = 0.0f; a1[d] = 0.0f; }
            #pragma unroll
            for (int e = 0; e < DIM; ++e) {
                const float re = r[e];
                #pragma unroll
                for (int d = 0; d < DIM; ++d) {
                    a0[d] = fmaf(w[d * 16 + e],     re, a0[d]);   // f = 0
                    a1[d] = fmaf(w[d * 16 + 8 + e], re, a1[d]);   // f = 1
                }
            }
            #pragma unroll
            for (int d = 0; d < DIM; ++d)
                r[d] = fmaf(qi, a0[d], pi * a1[d]);
        }
        #pragma unroll
        for (int d = 0; d < DIM; ++d) rv[lane][d] = r[d];
    }

    __syncthreads();

    // ---- label-site combine: out[o] = sum_{d,e} vl[d] * Mlab[d,e,o] * rv[e]
    // 128 threads cover 64 batches x 2 halves of the O dimension (5 each).
    {
        const int bb = threadIdx.x & 63;
        const int oh = threadIdx.x >> 6;          // 0 -> o 0..4, 1 -> o 5..9
        const int b2 = base + bb;
        const float p = x[(size_t)b2 * NSITES + LABEL];
        const float q = 1.0f - p;

        float vv[DIM], rr[DIM];
        #pragma unroll
        for (int d = 0; d < DIM; ++d) { vv[d] = vl[bb][d]; rr[d] = rv[bb][d]; }

        float acc[5];
        #pragma unroll
        for (int k = 0; k < 5; ++k) acc[k] = 0.0f;

        #pragma unroll
        for (int d = 0; d < DIM; ++d) {
            #pragma unroll
            for (int e = 0; e < DIM; ++e) {
                const float z = vv[d] * rr[e];
                const float* w0p = wlab + ((size_t)(d * 2 + 0) * DIM + e) * ODIM + oh * 5;
                const float* w1p = wlab + ((size_t)(d * 2 + 1) * DIM + e) * ODIM + oh * 5;
                #pragma unroll
                for (int k = 0; k < 5; ++k) {
                    const float m = fmaf(p, w1p[k], q * w0p[k]);  // q*W0 + p*W1
                    acc[k] = fmaf(z, m, acc[k]);
                }
            }
        }
        #pragma unroll
        for (int k = 0; k < 5; ++k)
            out[(size_t)b2 * ODIM + oh * 5 + k] = acc[k];
    }
}

extern "C" void kernel_launch(void* const* d_in, const int* in_sizes, int n_in,
                              void* d_out, int out_size, void* d_ws, size_t ws_size,
                              hipStream_t stream) {
    const float* x     = (const float*)d_in[0];  // [B, N, 1]
    const float* w0    = (const float*)d_in[1];  // [2, D]
    const float* Wl    = (const float*)d_in[2];  // [L_LEFT, D, 2, D]
    const float* wlab  = (const float*)d_in[3];  // [D, 2, D, O]
    const float* Wr    = (const float*)d_in[4];  // [L_RIGHT, D, 2, D]
    const float* wlast = (const float*)d_in[5];  // [D, 2]
    float* out = (float*)d_out;

    mps_chain_kernel<<<BATCH / 64, 128, 0, stream>>>(x, w0, Wl, wlab, Wr, wlast, out);
}